// Round 7
// baseline (48.640 us; speedup 1.0000x reference)
//
#include <hip/hip_runtime.h>
#include <math.h>

typedef __attribute__((ext_vector_type(8))) short short8;
typedef __attribute__((ext_vector_type(4))) float f32x4;
typedef __attribute__((ext_vector_type(4))) unsigned short u16x4;

// Problem constants: B=2, L=2048, H=8, D=64, M=128.
constexpr int B_ = 2, L_ = 2048, H_ = 8, D_ = 64, M_ = 128;
constexpr int T_ = 64;            // chunk length
constexpr int C_ = L_ / T_;       // 32 chunks
constexpr float DN_ = 0.35355339059327373f;     // 64^-0.25
constexpr float RATIO_ = 0.08838834764831845f;  // 1/sqrt(128)
constexpr float EPSV_ = 1e-6f;
constexpr float REPS_ = RATIO_ * EPSV_;   // ratio*eps: k' additive floor
constexpr float KEPS_ = 64.0f * REPS_;    // per-chunk ks eps mass

__device__ inline unsigned short f2bf(float x) {  // RNE float->bf16
  const unsigned u = __float_as_uint(x);
  return (unsigned short)((u + 0x7fffu + ((u >> 16) & 1u)) >> 16);
}
__device__ inline float bf2f(unsigned short h) {
  return __uint_as_float(((unsigned)h) << 16);
}

// One-time P hi/lo bf16 split (removes per-block conversion in feat).
__global__ __launch_bounds__(256) void psplit_kernel(
    const float* __restrict__ P, unsigned short* __restrict__ Ph,
    unsigned short* __restrict__ Pl) {
  const int i = blockIdx.x * 256 + threadIdx.x;  // over 2048 f32x4
  const f32x4 t4 = *reinterpret_cast<const f32x4*>(&P[(size_t)i * 4]);
  u16x4 hi, lo;
#pragma unroll
  for (int j = 0; j < 4; ++j) {
    hi[j] = f2bf(t4[j]);
    lo[j] = f2bf(t4[j] - bf2f(hi[j]));
  }
  *reinterpret_cast<u16x4*>(&Ph[(size_t)i * 4]) = hi;
  *reinterpret_cast<u16x4*>(&Pl[(size_t)i * 4]) = lo;
}

// Fused feature kernel, Q+K merged: grid 512, block = one (bh, chunk).
// Phases: stage P(hi/lo bf16)+X(q) -> Q dash MFMA -> q' out (LDS repack);
// restage X(k) -> K dash MFMA -> kpE/blockmax/kpT,V^T -> KV MFMA -> kvc/ks/vsum.
// LDS 55.3KB -> 2 blocks/CU; 512 blocks = exactly one full residency round.
__global__ __launch_bounds__(256) void feat_kernel(
    const float* __restrict__ q, const float* __restrict__ k,
    const unsigned short* __restrict__ Ph, const unsigned short* __restrict__ Pl,
    const float* __restrict__ v, unsigned short* __restrict__ qp16,
    unsigned short* __restrict__ kp16, unsigned short* __restrict__ kvc16,
    float* __restrict__ ksc, unsigned short* __restrict__ vt16,
    float* __restrict__ blockmax, float* __restrict__ vsum) {
  // flat LDS (shorts): XH[64x72]@0, XL[64x72]@4608, PH[128x72]@9216,
  // PL[128x72]@18432. Aliases: QPST[64][136]@0 (over XH+XL);
  // VT[64][72]@0 (over XH); KPT[128][72]@9216 (over PH);
  // KVST[64][136]@18432 (over PL).
  __shared__ __align__(16) unsigned short sm[27648];
  __shared__ float diag_s[T_];
  __shared__ float wred_s[2][T_];
  __shared__ float red4_s[4];

  const int sub = blockIdx.x;
  const int c = sub % C_, bh = sub / C_;
  const int b = bh >> 3, h = bh & 7;
  const int tid = threadIdx.x;
  const int w = tid >> 6, lane = tid & 63;
  const int l15 = lane & 15, l16 = lane >> 4;
  const int rblk = (w >> 1) * 32, cblk = (w & 1) * 64;

  // stage P hi/lo (vectorized bf16 loads)
  for (int i8 = tid; i8 < M_ * 8; i8 += 256) {
    const int m = i8 >> 3, d0 = (i8 & 7) * 8;
    *reinterpret_cast<short8*>(&sm[9216 + m * 72 + d0]) =
        *reinterpret_cast<const short8*>(&Ph[m * D_ + d0]);
    *reinterpret_cast<short8*>(&sm[18432 + m * 72 + d0]) =
        *reinterpret_cast<const short8*>(&Pl[m * D_ + d0]);
  }

#define STAGE_X(xptr)                                                         \
  for (int i4 = tid; i4 < T_ * 16; i4 += 256) {                               \
    const int r = i4 >> 4, d0 = (i4 & 15) * 4;                                \
    f32x4 t4 = *reinterpret_cast<const f32x4*>(                               \
        &(xptr)[((size_t)(b * L_ + c * T_ + r) * H_ + h) * D_ + d0]);         \
    u16x4 hi, lo;                                                             \
    float sq = 0.f;                                                           \
    _Pragma("unroll") for (int j = 0; j < 4; ++j) {                           \
      const float xv = t4[j] * DN_;                                           \
      sq += xv * xv;                                                          \
      const unsigned short hb = f2bf(xv);                                     \
      hi[j] = hb;                                                             \
      lo[j] = f2bf(xv - bf2f(hb));                                            \
    }                                                                         \
    *reinterpret_cast<u16x4*>(&sm[r * 72 + d0]) = hi;                         \
    *reinterpret_cast<u16x4*>(&sm[4608 + r * 72 + d0]) = lo;                  \
    _Pragma("unroll") for (int off = 1; off < 16; off <<= 1)                  \
        sq += __shfl_xor(sq, off, 64);                                        \
    if ((tid & 15) == 0) diag_s[r] = sq;                                      \
  }

#define DASH_MFMA(accv)                                                       \
  _Pragma("unroll") for (int kk = 0; kk < 2; ++kk) {                          \
    short8 ah[2], al[2], bh8[4], bl8[4];                                      \
    _Pragma("unroll") for (int ti = 0; ti < 2; ++ti) {                        \
      ah[ti] = *reinterpret_cast<const short8*>(                              \
          &sm[(rblk + ti * 16 + l15) * 72 + kk * 32 + l16 * 8]);              \
      al[ti] = *reinterpret_cast<const short8*>(                              \
          &sm[4608 + (rblk + ti * 16 + l15) * 72 + kk * 32 + l16 * 8]);       \
    }                                                                         \
    _Pragma("unroll") for (int tj = 0; tj < 4; ++tj) {                        \
      bh8[tj] = *reinterpret_cast<const short8*>(                             \
          &sm[9216 + (cblk + tj * 16 + l15) * 72 + kk * 32 + l16 * 8]);       \
      bl8[tj] = *reinterpret_cast<const short8*>(                             \
          &sm[18432 + (cblk + tj * 16 + l15) * 72 + kk * 32 + l16 * 8]);      \
    }                                                                         \
    _Pragma("unroll") for (int ti = 0; ti < 2; ++ti)                          \
        _Pragma("unroll") for (int tj = 0; tj < 4; ++tj) {                    \
      accv[ti][tj] = __builtin_amdgcn_mfma_f32_16x16x32_bf16(                 \
          al[ti], bh8[tj], accv[ti][tj], 0, 0, 0);                            \
      accv[ti][tj] = __builtin_amdgcn_mfma_f32_16x16x32_bf16(                 \
          ah[ti], bl8[tj], accv[ti][tj], 0, 0, 0);                            \
      accv[ti][tj] = __builtin_amdgcn_mfma_f32_16x16x32_bf16(                 \
          ah[ti], bh8[tj], accv[ti][tj], 0, 0, 0);                            \
    }                                                                         \
  }

  // ======== Q phase ========
  STAGE_X(q);
  __syncthreads();
  f32x4 acc[2][4];
#pragma unroll
  for (int i = 0; i < 2; ++i)
#pragma unroll
    for (int j = 0; j < 4; ++j) acc[i][j] = {0.f, 0.f, 0.f, 0.f};
  DASH_MFMA(acc);

  {  // per-row stab
    float rmax[2][4];
#pragma unroll
    for (int ti = 0; ti < 2; ++ti)
#pragma unroll
      for (int j = 0; j < 4; ++j) {
        float m0 = fmaxf(fmaxf(acc[ti][0][j], acc[ti][1][j]),
                         fmaxf(acc[ti][2][j], acc[ti][3][j]));
#pragma unroll
        for (int off = 1; off < 16; off <<= 1)
          m0 = fmaxf(m0, __shfl_xor(m0, off, 64));
        rmax[ti][j] = m0;
      }
    if (l15 == 0) {
#pragma unroll
      for (int ti = 0; ti < 2; ++ti)
#pragma unroll
        for (int j = 0; j < 4; ++j)
          wred_s[w & 1][rblk + ti * 16 + l16 * 4 + j] = rmax[ti][j];
    }
    __syncthreads();  // wred visible; all MFMA reads of XH/XL done
#pragma unroll
    for (int ti = 0; ti < 2; ++ti)
#pragma unroll
      for (int j = 0; j < 4; ++j) {
        const int row = rblk + ti * 16 + l16 * 4 + j;
        const float sub2 =
            0.5f * diag_s[row] + fmaxf(wred_s[0][row], wred_s[1][row]);
#pragma unroll
        for (int tj = 0; tj < 4; ++tj) {
          const int col = cblk + tj * 16 + l15;
          sm[row * 136 + col] =  // QPST repack (aliases XH/XL)
              f2bf(RATIO_ * (expf(acc[ti][tj][j] - sub2) + EPSV_));
        }
      }
    __syncthreads();
    unsigned short* outr = qp16 + ((size_t)bh * L_ + c * T_) * M_;
    for (int i8 = tid; i8 < T_ * 16; i8 += 256) {
      const int row = i8 >> 4, m0 = (i8 & 15) * 8;
      *reinterpret_cast<short8*>(&outr[row * M_ + m0]) =
          *reinterpret_cast<const short8*>(&sm[row * 136 + m0]);
    }
  }
  __syncthreads();  // QPST reads done; safe to restage X

  // ======== K phase ========
  STAGE_X(k);
  __syncthreads();
#pragma unroll
  for (int i = 0; i < 2; ++i)
#pragma unroll
    for (int j = 0; j < 4; ++j) acc[i][j] = {0.f, 0.f, 0.f, 0.f};
  DASH_MFMA(acc);

  float bm = -INFINITY;
#pragma unroll
  for (int ti = 0; ti < 2; ++ti)
#pragma unroll
    for (int tj = 0; tj < 4; ++tj)
#pragma unroll
      for (int j = 0; j < 4; ++j) bm = fmaxf(bm, acc[ti][tj][j]);
#pragma unroll
  for (int off = 1; off < 64; off <<= 1) bm = fmaxf(bm, __shfl_xor(bm, off, 64));
  if (lane == 0) red4_s[w] = bm;
  __syncthreads();  // red4 visible AND all MFMA reads of PH/XH done
  const float lmax =
      fmaxf(fmaxf(red4_s[0], red4_s[1]), fmaxf(red4_s[2], red4_s[3]));
  if (tid == 0) blockmax[sub] = lmax;

  // kpE (NO eps) -> global + KPT (aliases PH); stage V^T (aliases XH)
  unsigned short* kpr = kp16 + ((size_t)bh * L_ + c * T_) * M_;
#pragma unroll
  for (int ti = 0; ti < 2; ++ti)
#pragma unroll
    for (int j = 0; j < 4; ++j) {
      const int row = rblk + ti * 16 + l16 * 4 + j;
      const float sub2 = 0.5f * diag_s[row] + lmax;
#pragma unroll
      for (int tj = 0; tj < 4; ++tj) {
        const int col = cblk + tj * 16 + l15;
        const unsigned short us = f2bf(RATIO_ * expf(acc[ti][tj][j] - sub2));
        kpr[row * M_ + col] = us;
        sm[9216 + col * 72 + row] = us;  // KPT[m][t]
      }
    }
  for (int i = tid; i < T_ * D_; i += 256) {
    const int t = i & 63, d = i >> 6;
    sm[d * 72 + t] =  // VT[d][t]
        f2bf(v[((size_t)(b * L_ + c * T_ + t) * H_ + h) * D_ + d]);
  }
  __syncthreads();

  unsigned short* vg = vt16 + (size_t)(bh * C_ + c) * (D_ * T_);
  for (int i8 = tid; i8 < D_ * 8; i8 += 256) {
    const int d = i8 >> 3, t0 = (i8 & 7) * 8;
    *reinterpret_cast<short8*>(&vg[d * T_ + t0]) =
        *reinterpret_cast<const short8*>(&sm[d * 72 + t0]);
  }
  if (tid < M_) {  // ksE[m]
    float s = 0.f;
#pragma unroll
    for (int t8 = 0; t8 < 8; ++t8) {
      const short8 h8 =
          *reinterpret_cast<const short8*>(&sm[9216 + tid * 72 + t8 * 8]);
#pragma unroll
      for (int j = 0; j < 8; ++j) s += bf2f((unsigned short)h8[j]);
    }
    ksc[(size_t)(bh * C_ + c) * M_ + tid] = s;
  }
  if (tid >= 128 && tid < 128 + D_) {  // Vsum[d]
    const int d = tid - 128;
    float s = 0.f;
#pragma unroll
    for (int t8 = 0; t8 < 8; ++t8) {
      const short8 h8 = *reinterpret_cast<const short8*>(&sm[d * 72 + t8 * 8]);
#pragma unroll
      for (int j = 0; j < 8; ++j) s += bf2f((unsigned short)h8[j]);
    }
    vsum[(size_t)(bh * C_ + c) * D_ + d] = s;
  }
  // KVE^T[d][m] = sum_t v[t,d]*kpE[t,m] (NT: A=VT rows d, B=KPT rows m)
  f32x4 acc2[2][4];
#pragma unroll
  for (int i = 0; i < 2; ++i)
#pragma unroll
    for (int j = 0; j < 4; ++j) acc2[i][j] = {0.f, 0.f, 0.f, 0.f};
#pragma unroll
  for (int kk = 0; kk < 2; ++kk) {
    short8 av[2], bv[4];
#pragma unroll
    for (int ti = 0; ti < 2; ++ti)
      av[ti] = *reinterpret_cast<const short8*>(
          &sm[(rblk + ti * 16 + l15) * 72 + kk * 32 + l16 * 8]);
#pragma unroll
    for (int tj = 0; tj < 4; ++tj)
      bv[tj] = *reinterpret_cast<const short8*>(
          &sm[9216 + (cblk + tj * 16 + l15) * 72 + kk * 32 + l16 * 8]);
#pragma unroll
    for (int ti = 0; ti < 2; ++ti)
#pragma unroll
      for (int tj = 0; tj < 4; ++tj)
        acc2[ti][tj] = __builtin_amdgcn_mfma_f32_16x16x32_bf16(
            av[ti], bv[tj], acc2[ti][tj], 0, 0, 0);
  }
  // repack KVST (aliases PL; PL dead since dash MFMA) -> vector store
#pragma unroll
  for (int ti = 0; ti < 2; ++ti)
#pragma unroll
    for (int j = 0; j < 4; ++j) {
      const int row = rblk + ti * 16 + l16 * 4 + j;  // d
#pragma unroll
      for (int tj = 0; tj < 4; ++tj) {
        const int col = cblk + tj * 16 + l15;  // m
        sm[18432 + row * 136 + col] = f2bf(acc2[ti][tj][j]);
      }
    }
  __syncthreads();
  unsigned short* ob = kvc16 + (size_t)(bh * C_ + c) * (M_ * D_);
  for (int i8 = tid; i8 < D_ * 16; i8 += 256) {
    const int d = i8 >> 4, m0 = (i8 & 15) * 8;
    *reinterpret_cast<short8*>(&ob[d * M_ + m0]) =
        *reinterpret_cast<const short8*>(&sm[18432 + d * 136 + m0]);
  }
#undef STAGE_X
#undef DASH_MFMA
}

// Exclusive prefix across chunks with exact eps terms (as round 6).
__global__ __launch_bounds__(256) void prefix_kernel(
    const unsigned short* __restrict__ kvc16,
    unsigned short* __restrict__ kvp16, float* __restrict__ ksc,
    const float* __restrict__ blockmax, const float* __restrict__ vsum) {
  __shared__ float bm_s[C_];
  __shared__ float sc_s[C_];
  __shared__ float vs_s[2][C_];
  const int bid = blockIdx.x;  // B*H*32
  const int ej = bid & 31, bh = bid >> 5;
  if (threadIdx.x < C_) bm_s[threadIdx.x] = blockmax[bh * C_ + threadIdx.x];
  if (threadIdx.x >= 64 && threadIdx.x < 64 + 2 * C_) {
    const int t = threadIdx.x - 64;
    const int ld = t >> 5, cc = t & 31;
    vs_s[ld][cc] = vsum[(size_t)(bh * C_ + cc) * D_ + ej * 2 + ld];
  }
  __syncthreads();
  if (threadIdx.x < C_) {
    float km = -INFINITY;
#pragma unroll
    for (int cc = 0; cc < C_; ++cc) km = fmaxf(km, bm_s[cc]);
    sc_s[threadIdx.x] = expf(bm_s[threadIdx.x] - km);
  }
  __syncthreads();
  const int e = ej * 256 + threadIdx.x;
  const int dl = threadIdx.x >> 7;
  float vals[C_];
#pragma unroll
  for (int cc = 0; cc < C_; ++cc)
    vals[cc] = bf2f(kvc16[(size_t)(bh * C_ + cc) * (M_ * D_) + e]) * sc_s[cc] +
               REPS_ * vs_s[dl][cc];
  float run = 0.f;
#pragma unroll
  for (int cc = 0; cc < C_; ++cc) {
    const float t = vals[cc];
    vals[cc] = run;
    run += t;
  }
#pragma unroll
  for (int cc = 0; cc < C_; ++cc)
    kvp16[(size_t)(bh * C_ + cc) * (M_ * D_) + e] = f2bf(vals[cc]);
  if (ej == 0 && threadIdx.x < M_) {
    const int m = threadIdx.x;
    float ks[C_];
#pragma unroll
    for (int cc = 0; cc < C_; ++cc)
      ks[cc] = ksc[(size_t)(bh * C_ + cc) * M_ + m] * sc_s[cc] + KEPS_;
    float rs = 0.f;
#pragma unroll
    for (int cc = 0; cc < C_; ++cc) {
      const float t = ks[cc];
      ks[cc] = rs;
      rs += t;
    }
#pragma unroll
    for (int cc = 0; cc < C_; ++cc)
      ksc[(size_t)(bh * C_ + cc) * M_ + m] = ks[cc];
  }
}

// Intra-chunk MFMA. kvp and V^T fragments read DIRECTLY from global (each
// used once per wave -> LDS staging was pure overhead); LDS 46KB -> 3 blk/CU.
__global__ __launch_bounds__(256, 3) void intra_kernel(
    const unsigned short* __restrict__ qp16,
    const unsigned short* __restrict__ kp16,
    const unsigned short* __restrict__ vt16,
    const unsigned short* __restrict__ kvp16, const float* __restrict__ ksp,
    const float* __restrict__ blockmax, float* __restrict__ out) {
  __shared__ __align__(16) unsigned short qp_s[T_][136];
  __shared__ __align__(16) unsigned short kp_s[T_][136];
  __shared__ __align__(16) unsigned short S_s[T_][72];
  __shared__ float ksp_s[M_];
  __shared__ float denp_s[4][T_];
  __shared__ float den_s[T_];
  __shared__ float qsum_s[T_];
  __shared__ float bm_s[C_];

  const int bid = blockIdx.x;
  const int c = bid % C_, bh = bid / C_;
  const int b = bh >> 3, h = bh & 7;
  const int tid = threadIdx.x;
  const int w = tid >> 6, lane = tid & 63;
  const int l15 = lane & 15, l16 = lane >> 4;

  const unsigned short* qpt = qp16 + ((size_t)bh * L_ + c * T_) * M_;
  const unsigned short* kpt = kp16 + ((size_t)bh * L_ + c * T_) * M_;
  const unsigned short* kvt = kvp16 + (size_t)(bh * C_ + c) * (M_ * D_);
  const unsigned short* vg = vt16 + (size_t)(bh * C_ + c) * (D_ * T_);

  if (tid < C_) bm_s[tid] = blockmax[bh * C_ + tid];
  for (int i8 = tid; i8 < T_ * 16; i8 += 256) {
    const int r = i8 >> 4, m0 = (i8 & 15) * 8;
    *reinterpret_cast<short8*>(&qp_s[r][m0]) =
        *reinterpret_cast<const short8*>(&qpt[r * M_ + m0]);
    *reinterpret_cast<short8*>(&kp_s[r][m0]) =
        *reinterpret_cast<const short8*>(&kpt[r * M_ + m0]);
  }
  if (tid < M_) ksp_s[tid] = ksp[(size_t)(bh * C_ + c) * M_ + tid];
  __syncthreads();

  // qsum[t] via 4-lane groups (wave w owns rows w*16..+15)
  {
    const int row = w * 16 + (lane >> 2), mseg = (lane & 3) * 32;
    float p = 0.f;
#pragma unroll
    for (int u = 0; u < 4; ++u) {
      const short8 h8 =
          *reinterpret_cast<const short8*>(&qp_s[row][mseg + u * 8]);
#pragma unroll
      for (int j = 0; j < 8; ++j) p += bf2f((unsigned short)h8[j]);
    }
    p += __shfl_xor(p, 1, 64);
    p += __shfl_xor(p, 2, 64);
    if ((lane & 3) == 0) qsum_s[row] = p;
  }
  __syncthreads();

  float km = -INFINITY;
#pragma unroll
  for (int cc = 0; cc < C_; ++cc) km = fmaxf(km, bm_s[cc]);
  const float sc = expf(bm_s[c] - km);

  const int rblk = (w >> 1) * 32, cblk = (w & 1) * 32;
  f32x4 Sacc[2][2];
#pragma unroll
  for (int i = 0; i < 2; ++i)
#pragma unroll
    for (int j = 0; j < 2; ++j) Sacc[i][j] = {0.f, 0.f, 0.f, 0.f};

#pragma unroll
  for (int kk = 0; kk < 4; ++kk) {
    short8 af[2], bf[2];
#pragma unroll
    for (int ti = 0; ti < 2; ++ti)
      af[ti] = *reinterpret_cast<const short8*>(
          &qp_s[rblk + ti * 16 + l15][kk * 32 + l16 * 8]);
#pragma unroll
    for (int tj = 0; tj < 2; ++tj)
      bf[tj] = *reinterpret_cast<const short8*>(
          &kp_s[cblk + tj * 16 + l15][kk * 32 + l16 * 8]);
#pragma unroll
    for (int ti = 0; ti < 2; ++ti)
#pragma unroll
      for (int tj = 0; tj < 2; ++tj)
        Sacc[ti][tj] = __builtin_amdgcn_mfma_f32_16x16x32_bf16(
            af[ti], bf[tj], Sacc[ti][tj], 0, 0, 0);
  }
#pragma unroll
  for (int ti = 0; ti < 2; ++ti)
#pragma unroll
    for (int tj = 0; tj < 2; ++tj)
#pragma unroll
      for (int j = 0; j < 4; ++j) {
        const int row = rblk + ti * 16 + l16 * 4 + j;
        const int col = cblk + tj * 16 + l15;
        const float add = REPS_ * qsum_s[row];
        const float sv = (col <= row) ? Sacc[ti][tj][j] * sc + add : 0.f;
        S_s[row][col] = f2bf(sv);
      }
  __syncthreads();

  {
    const int t = lane;
    float p = 0.f;
    if (w == 0) {
      for (int tp = 0; tp < 32; ++tp) p += bf2f(S_s[t][tp]);
    } else if (w == 1) {
      for (int tp = 32; tp < 64; ++tp) p += bf2f(S_s[t][tp]);
    } else if (w == 2) {
      for (int m = 0; m < 64; ++m) p += bf2f(qp_s[t][m]) * ksp_s[m];
    } else {
      for (int m = 64; m < 128; ++m) p += bf2f(qp_s[t][m]) * ksp_s[m];
    }
    denp_s[w][t] = p;
  }
  __syncthreads();
  if (tid < T_)
    den_s[tid] =
        denp_s[0][tid] + denp_s[1][tid] + denp_s[2][tid] + denp_s[3][tid];
  __syncthreads();

  const int dblk = (w & 1) * 32;
  f32x4 Nacc[2][2];
#pragma unroll
  for (int i = 0; i < 2; ++i)
#pragma unroll
    for (int j = 0; j < 2; ++j) Nacc[i][j] = {0.f, 0.f, 0.f, 0.f};

#pragma unroll
  for (int kk = 0; kk < 2; ++kk) {  // S @ V^T (V frags from global)
    short8 af[2], bf[2];
#pragma unroll
    for (int ti = 0; ti < 2; ++ti)
      af[ti] = *reinterpret_cast<const short8*>(
          &S_s[rblk + ti * 16 + l15][kk * 32 + l16 * 8]);
#pragma unroll
    for (int tj = 0; tj < 2; ++tj)
      bf[tj] = *reinterpret_cast<const short8*>(
          &vg[(dblk + tj * 16 + l15) * T_ + kk * 32 + l16 * 8]);
#pragma unroll
    for (int ti = 0; ti < 2; ++ti)
#pragma unroll
      for (int tj = 0; tj < 2; ++tj)
        Nacc[ti][tj] = __builtin_amdgcn_mfma_f32_16x16x32_bf16(
            af[ti], bf[tj], Nacc[ti][tj], 0, 0, 0);
  }
#pragma unroll
  for (int kk = 0; kk < 4; ++kk) {  // qp @ KVp^T (KV frags from global)
    short8 af[2], bf[2];
#pragma unroll
    for (int ti = 0; ti < 2; ++ti)
      af[ti] = *reinterpret_cast<const short8*>(
          &qp_s[rblk + ti * 16 + l15][kk * 32 + l16 * 8]);
#pragma unroll
    for (int tj = 0; tj < 2; ++tj)
      bf[tj] = *reinterpret_cast<const short8*>(
          &kvt[(dblk + tj * 16 + l15) * M_ + kk * 32 + l16 * 8]);
#pragma unroll
    for (int ti = 0; ti < 2; ++ti)
#pragma unroll
      for (int tj = 0; tj < 2; ++tj)
        Nacc[ti][tj] = __builtin_amdgcn_mfma_f32_16x16x32_bf16(
            af[ti], bf[tj], Nacc[ti][tj], 0, 0, 0);
  }

#pragma unroll
  for (int ti = 0; ti < 2; ++ti)
#pragma unroll
    for (int j = 0; j < 4; ++j) {
      const int row = rblk + ti * 16 + l16 * 4 + j;
      const float r = 1.f / den_s[row];
      float* orow = out + ((size_t)(b * L_ + c * T_ + row) * H_ + h) * D_;
#pragma unroll
      for (int tj = 0; tj < 2; ++tj) {
        const int col = dblk + tj * 16 + l15;
        orow[col] = Nacc[ti][tj][j] * r;
      }
    }
}

extern "C" void kernel_launch(void* const* d_in, const int* in_sizes, int n_in,
                              void* d_out, int out_size, void* d_ws,
                              size_t ws_size, hipStream_t stream) {
  const float* q = (const float*)d_in[0];
  const float* k = (const float*)d_in[1];
  const float* v = (const float*)d_in[2];
  const float* P = (const float*)d_in[3];
  float* out = (float*)d_out;

  float* ws = (float*)d_ws;
  float* blockmax = ws;                                   // 512
  float* ksp = blockmax + 512;                            // B*H*C*M
  float* vsum = ksp + (size_t)B_ * H_ * C_ * M_;          // B*H*C*D
  unsigned short* Ph16 = (unsigned short*)(vsum + (size_t)B_ * H_ * C_ * D_);
  unsigned short* Pl16 = Ph16 + M_ * D_;
  unsigned short* qp16 = Pl16 + M_ * D_;
  unsigned short* kp16 = qp16 + (size_t)B_ * H_ * L_ * M_;
  unsigned short* kvc16 = kp16 + (size_t)B_ * H_ * L_ * M_;
  unsigned short* kvp16 = kvc16 + (size_t)B_ * H_ * C_ * D_ * M_;
  unsigned short* vt16 = kvp16 + (size_t)B_ * H_ * C_ * D_ * M_;

  psplit_kernel<<<M_ * D_ / 1024, 256, 0, stream>>>(P, Ph16, Pl16);
  feat_kernel<<<B_ * H_ * C_, 256, 0, stream>>>(q, k, Ph16, Pl16, v, qp16,
                                                kp16, kvc16, ksp, vt16,
                                                blockmax, vsum);
  prefix_kernel<<<B_ * H_ * 32, 256, 0, stream>>>(kvc16, kvp16, ksp, blockmax,
                                                  vsum);
  intra_kernel<<<B_ * H_ * C_, 256, 0, stream>>>(qp16, kp16, vt16, kvp16, ksp,
                                                 blockmax, out);
}